// Round 8
// baseline (330.180 us; speedup 1.0000x reference)
//
#include <hip/hip_runtime.h>
#include <cstdint>

#define C_     512
#define HW_    784
#define HW2_   392                 // HW_/2 : float2 elements per (b,c) plane
#define B_     64
#define BN_EPS 1e-5f

// Workspace layout:
//   [0, 32768)     : wbits   uint32[512][16]  (bit c%32 of word c/32 = 1 iff W[o][c] < 0)
//   [32768, 40960) : params  float4[512]      {A2, C2, slope, bias}
//
// Math folding:
//   scale[o] = mean|W[o,:]| ; S = 512 - 2*P (P = popcount(a^wsign)) ; y = scale*S
//   bn = A*S + B2,  A = gamma*scale*r, B2 = beta - gamma*mean*r
//   t  = bn + x - shift = (-2A)*P + (512A + B2 - shift) + x = A2*P + C2 + x
//   out = max(t,0) + slope*min(t,0) + bias   (branchless RPReLU)
//
// Journal:
//   R1: nontemporal stores -> WRITE 100->238 MB + L3 eviction. Never again.
//   R2: xv[32] reg-cache defeated by remat under 64-VGPR cap. 83.3 us. BEST.
//   R3: sw-pipeline flattened by regalloc; L2 thrash. 113 us.
//   R4: asm-pin sank past barrier with the loads; half occupancy. 97 us.
//   R5: split kernels: scheduler still caps ~8 loads in flight. REVERTED.
//   R6: LDS-staging wbits/params: DEAD (FETCH +121 MB, conflicts). 137 us.
//   R7: LDS-staging x (VGPR=52, phase 2 truly global-load-free): 102 us at
//       occ 33%. FETCH/WRITE byte-identical to R2 -> the phase-2 re-read was
//       ALREADY free (L3-absorbed); staging only cost occupancy.
//   SURVIVING MODEL: Little's-law deficit. Every round used 4 B/lane loads
//       (256 B/wave-instr) with a compiler-enforced ~8-deep load window ->
//       ~2 KB outstanding/wave, far under what 6.3 TB/s at ~800 ns needs.
//       Load COUNT is compiler-capped (R2/R3/R4/R5 proved it); bytes/load
//       is compiler-proof.
//   R8 (this): float2 over hw everywhere. Lane = duo of 2 consecutive pairs
//       (784 even -> a duo never straddles a batch image). 392 blocks of
//       (64,16) -> ALL blocks co-resident in ONE dispatch round. Phase-2
//       x re-read stays R2's consume-immediate pattern (it's L2-hot and
//       free). vmem instruction count halves; bytes/request double.
//       Tell: dur ~55-65 = theory right; dur ~83 = pattern-intrinsic wall,
//       declare roofline next round.

__global__ __launch_bounds__(64) void precompute_kernel(
    const float* __restrict__ W,
    const float* __restrict__ bn_gamma, const float* __restrict__ bn_beta,
    const float* __restrict__ bn_mean,  const float* __restrict__ bn_var,
    const float* __restrict__ pr_slope, const float* __restrict__ pr_shift,
    const float* __restrict__ pr_bias,
    uint32_t* __restrict__ wbits, float4* __restrict__ params)
{
    const int o    = blockIdx.x;
    const int lane = threadIdx.x;
    const float4* wrow4 = (const float4*)(W + (size_t)o * C_);
    const float4 u = wrow4[2 * lane];
    const float4 v = wrow4[2 * lane + 1];

    float s = fabsf(u.x) + fabsf(u.y) + fabsf(u.z) + fabsf(u.w)
            + fabsf(v.x) + fabsf(v.y) + fabsf(v.z) + fabsf(v.w);
    for (int off = 32; off > 0; off >>= 1) s += __shfl_down(s, off, 64);

    uint32_t m8 = (u.x < 0.f ? 1u : 0u)  | (u.y < 0.f ? 2u : 0u)
                | (u.z < 0.f ? 4u : 0u)  | (u.w < 0.f ? 8u : 0u)
                | (v.x < 0.f ? 16u : 0u) | (v.y < 0.f ? 32u : 0u)
                | (v.z < 0.f ? 64u : 0u) | (v.w < 0.f ? 128u : 0u);

    const uint32_t g0 = __shfl(m8, 4 * lane + 0, 64);
    const uint32_t g1 = __shfl(m8, 4 * lane + 1, 64);
    const uint32_t g2 = __shfl(m8, 4 * lane + 2, 64);
    const uint32_t g3 = __shfl(m8, 4 * lane + 3, 64);
    if (lane < 16)
        wbits[o * 16 + lane] = g0 | (g1 << 8) | (g2 << 16) | (g3 << 24);

    if (lane == 0) {
        float scale = s * (1.0f / (float)C_);
        float r  = rsqrtf(bn_var[o] + BN_EPS);
        float A  = bn_gamma[o] * scale * r;
        float A2 = -2.0f * A;
        float C2 = (float)C_ * A + bn_beta[o] - bn_gamma[o] * bn_mean[o] * r
                 - pr_shift[o];
        params[o] = make_float4(A2, C2, pr_slope[o], pr_bias[o]);
    }
}

// Block: (64 lanes) x (16 waves) = 1024 threads; grid = 392 blocks covering
// the 25,088 hw-duos exactly (392*64). Wave jj binarizes channels
// [32jj, 32jj+32) for its 64 duos (128 pairs) and computes outputs for those
// same channels. All float2 accesses are 8B-aligned (hw even).
// LDS: two R2-proven [64][17] bit tiles (one per duo half), 8.7 KB total;
// 2 blocks/CU (thread-capped), occupancy structure as R2 but single-round.
__global__ __launch_bounds__(1024, 8) void fused_kernel(
    const float* __restrict__ x, const float* __restrict__ rsign_bias,
    const uint32_t* __restrict__ wbits, const float4* __restrict__ params,
    float* __restrict__ out)
{
    __shared__ uint32_t abits0[64 * 17];   // bits for even hw of each duo
    __shared__ uint32_t abits1[64 * 17];   // bits for odd  hw of each duo

    const int i  = threadIdx.x;                                   // duo lane
    const int jj = __builtin_amdgcn_readfirstlane(threadIdx.y);   // wave 0..15

    const uint32_t duo = (uint32_t)blockIdx.x * 64u + (uint32_t)i;
    const uint32_t b   = duo / 392u;            // magic-mul division
    const uint32_t hw2 = duo - b * 392u;        // float2 index within plane
    const float2* xg = (const float2*)x   + (size_t)b * (C_ * HW2_) + hw2;
    float2*       og = (float2*)out       + (size_t)b * (C_ * HW2_) + hw2;

    const int c0 = jj * 32;                                       // wave-uniform

    // ---- Phase 1: binarize channels [c0, c0+32) for both duo halves ----
    // 32 float2 loads: 512 B/wave-instruction -> 2x outstanding bytes at the
    // same compiler-chosen load-window depth.
    {
        float2 v[32];
        #pragma unroll
        for (int t = 0; t < 32; ++t)
            v[t] = xg[(size_t)(c0 + t) * HW2_];

        uint32_t m0 = 0, m1 = 0;
        #pragma unroll
        for (int t = 0; t < 32; ++t) {
            const float rb = rsign_bias[c0 + t];          // s_load
            if (v[t].x + rb < 0.f) m0 |= (1u << t);
            if (v[t].y + rb < 0.f) m1 |= (1u << t);
        }
        abits0[i * 17 + jj] = m0;
        abits1[i * 17 + jj] = m1;
    }
    __syncthreads();

    // ---- Phase 2: both 512-bit activation rows from LDS; wbits/params via
    //      s_load (R2's proven path); x re-read float2 (L2-hot, consume-
    //      immediate -- R2 pattern); plain float2 stores (R1 lesson). ----
    uint32_t a0[16], a1[16];
    #pragma unroll
    for (int w = 0; w < 16; ++w) {
        a0[w] = abits0[i * 17 + w];
        a1[w] = abits1[i * 17 + w];
    }

    #pragma unroll
    for (int oo = 0; oo < 32; ++oo) {
        const int o = c0 + oo;                            // wave-uniform
        const uint32_t* wr = wbits + o * 16;              // s_load rows
        int P0 = 0, P1 = 0;
        #pragma unroll
        for (int w = 0; w < 16; ++w) {
            const uint32_t q = wr[w];                     // shared s_load
            P0 += __popc(a0[w] ^ q);
            P1 += __popc(a1[w] ^ q);
        }

        const float4 p = params[o];                       // s_load
        const float2 xr = xg[(size_t)o * HW2_];
        const float t0 = fmaf(p.x, (float)P0, p.y + xr.x);
        const float t1 = fmaf(p.x, (float)P1, p.y + xr.y);
        float2 r;
        r.x = fmaf(p.z, fminf(t0, 0.f), fmaxf(t0, 0.f) + p.w);
        r.y = fmaf(p.z, fminf(t1, 0.f), fmaxf(t1, 0.f) + p.w);
        og[(size_t)o * HW2_] = r;                         // 512 B/wave store
    }
}

extern "C" void kernel_launch(void* const* d_in, const int* in_sizes, int n_in,
                              void* d_out, int out_size, void* d_ws, size_t ws_size,
                              hipStream_t stream) {
    const float* x          = (const float*)d_in[0];
    const float* rsign_bias = (const float*)d_in[1];
    const float* W          = (const float*)d_in[2];
    const float* bn_gamma   = (const float*)d_in[3];
    const float* bn_beta    = (const float*)d_in[4];
    const float* bn_mean    = (const float*)d_in[5];
    const float* bn_var     = (const float*)d_in[6];
    const float* pr_slope   = (const float*)d_in[7];
    const float* pr_shift   = (const float*)d_in[8];
    const float* pr_bias    = (const float*)d_in[9];
    float* out = (float*)d_out;

    uint32_t* wbits  = (uint32_t*)d_ws;
    float4*   params = (float4*)((char*)d_ws + 32768);

    precompute_kernel<<<dim3(C_), dim3(64), 0, stream>>>(
        W, bn_gamma, bn_beta, bn_mean, bn_var, pr_slope, pr_shift, pr_bias,
        wbits, params);

    // 25088 hw-duos = 392 tiles of 64, zero waste; 1024-thr blocks, 2/CU,
    // ALL 392 blocks co-resident in a single dispatch round.
    fused_kernel<<<dim3(392), dim3(64, 16), 0, stream>>>(
        x, rsign_bias, wbits, params, out);
}